// Round 7
// baseline (849.528 us; speedup 1.0000x reference)
//
#include <hip/hip_runtime.h>
#include <hip/hip_bf16.h>
#include <cfloat>

#define Nn 2048
#define KK 20
#define BB 8
#define SLOPE 0.2f
#define NCH 32   // partial chunks in global conv (8 nblk x 4 waves)

typedef __bf16 bf16x8 __attribute__((ext_vector_type(8)));
typedef float f32x4 __attribute__((ext_vector_type(4)));
typedef unsigned long long u64;

// ---------------- weight stack: Wstk[c][o] = W[o][c]; Wstk[c][Co+o] = W[o][C+c]-W[o][c]
__global__ void wstack_kernel(const float* __restrict__ W, float* __restrict__ Wstk,
                              int Co, int C) {
    int i = blockIdx.x * 256 + threadIdx.x;
    if (i < Co * C) {
        int o = i / C, c = i - o * C;
        float a = W[(long)o * 2 * C + c];
        float bb = W[(long)o * 2 * C + C + c];
        Wstk[(long)c * 2 * Co + o] = a;
        Wstk[(long)c * 2 * Co + Co + o] = bb - a;
    }
}

// ---------------- fp32 -> bf16 copy ----------------
__global__ void tobf16_kernel(const float* __restrict__ A, __hip_bfloat16* __restrict__ B,
                              int n) {
    int i = blockIdx.x * 256 + threadIdx.x;
    if (i < n) B[i] = __float2bfloat16(A[i]);
}

// order-preserving float-bits -> u32 map (works for negatives)
__device__ __forceinline__ unsigned fkey(float f) {
    unsigned u = __float_as_uint(f);
    return u ^ (((unsigned)((int)u >> 31)) | 0x80000000u);
}

// ---------------- KNN distance + per-half top-20 ----------------
// block: 8 rows x 1024-j half, 256 thr (thread = 4 consecutive j, float4 load).
// dist order == xx_j - 2*dot(x_n, x_j). Writes sorted top-20 u64 (key<<32|j) per half.
template<int C>
__global__ void __launch_bounds__(256)
knn_dist_kernel(const float* __restrict__ x, long bstride,
                u64* __restrict__ halfsel) {
    __shared__ unsigned dist[8][1024];   // 32 KB
    const int tid = threadIdx.x;
    const int half = blockIdx.x & 1;
    const int ng = (blockIdx.x >> 1) & 255;
    const int b  = blockIdx.x >> 9;
    const int n0 = ng * 8;
    const int jbase = half * 1024;
    const int jl = tid * 4;
    const float* xb = x + (long)b * bstride;

    float acc[8][4];
    #pragma unroll
    for (int r = 0; r < 8; ++r)
        #pragma unroll
        for (int q = 0; q < 4; ++q) acc[r][q] = 0.f;
    float sq[4] = {0.f, 0.f, 0.f, 0.f};

    #pragma unroll 4
    for (int c = 0; c < C; ++c) {
        const float* xp = xb + (long)c * Nn;
        float4 xv = *(const float4*)(xp + jbase + jl);
        float4 c0 = *(const float4*)(xp + n0);      // block-uniform
        float4 c1 = *(const float4*)(xp + n0 + 4);
        sq[0] += xv.x * xv.x; sq[1] += xv.y * xv.y;
        sq[2] += xv.z * xv.z; sq[3] += xv.w * xv.w;
        acc[0][0] += c0.x * xv.x; acc[0][1] += c0.x * xv.y; acc[0][2] += c0.x * xv.z; acc[0][3] += c0.x * xv.w;
        acc[1][0] += c0.y * xv.x; acc[1][1] += c0.y * xv.y; acc[1][2] += c0.y * xv.z; acc[1][3] += c0.y * xv.w;
        acc[2][0] += c0.z * xv.x; acc[2][1] += c0.z * xv.y; acc[2][2] += c0.z * xv.z; acc[2][3] += c0.z * xv.w;
        acc[3][0] += c0.w * xv.x; acc[3][1] += c0.w * xv.y; acc[3][2] += c0.w * xv.z; acc[3][3] += c0.w * xv.w;
        acc[4][0] += c1.x * xv.x; acc[4][1] += c1.x * xv.y; acc[4][2] += c1.x * xv.z; acc[4][3] += c1.x * xv.w;
        acc[5][0] += c1.y * xv.x; acc[5][1] += c1.y * xv.y; acc[5][2] += c1.y * xv.z; acc[5][3] += c1.y * xv.w;
        acc[6][0] += c1.z * xv.x; acc[6][1] += c1.z * xv.y; acc[6][2] += c1.z * xv.z; acc[6][3] += c1.z * xv.w;
        acc[7][0] += c1.w * xv.x; acc[7][1] += c1.w * xv.y; acc[7][2] += c1.w * xv.z; acc[7][3] += c1.w * xv.w;
    }
    #pragma unroll
    for (int r = 0; r < 8; ++r) {
        uint4 kv;
        kv.x = fkey(fmaf(-2.f, acc[r][0], sq[0]));
        kv.y = fkey(fmaf(-2.f, acc[r][1], sq[1]));
        kv.z = fkey(fmaf(-2.f, acc[r][2], sq[2]));
        kv.w = fkey(fmaf(-2.f, acc[r][3], sq[3]));
        *(uint4*)(&dist[r][jl]) = kv;
    }
    __syncthreads();

    // selection: wave w handles rows 2w, 2w+1; lazy per-lane top-2 in registers.
    const int w = tid >> 6, lane = tid & 63;
    for (int rr = 0; rr < 2; ++rr) {
        const int row = w * 2 + rr;
        unsigned* drow = dist[row];
        u64* outp = halfsel + (((long)b * Nn + n0 + row) * 2 + half) * KK;

        auto scan2 = [&](u64& m1, u64& m2) {
            m1 = ~0ull; m2 = ~0ull;
            #pragma unroll
            for (int i = 0; i < 4; ++i) {
                int j4 = (i * 64 + lane) * 4;
                uint4 v = *(const uint4*)(drow + j4);
                u64 k0 = ((u64)v.x << 32) | (unsigned)(jbase + j4 + 0);
                u64 k1 = ((u64)v.y << 32) | (unsigned)(jbase + j4 + 1);
                u64 k2 = ((u64)v.z << 32) | (unsigned)(jbase + j4 + 2);
                u64 k3 = ((u64)v.w << 32) | (unsigned)(jbase + j4 + 3);
                u64 hi;
                hi = k0 > m1 ? k0 : m1; m1 = k0 < m1 ? k0 : m1; m2 = hi < m2 ? hi : m2;
                hi = k1 > m1 ? k1 : m1; m1 = k1 < m1 ? k1 : m1; m2 = hi < m2 ? hi : m2;
                hi = k2 > m1 ? k2 : m1; m1 = k2 < m1 ? k2 : m1; m2 = hi < m2 ? hi : m2;
                hi = k3 > m1 ? k3 : m1; m1 = k3 < m1 ? k3 : m1; m2 = hi < m2 ? hi : m2;
            }
        };

        u64 lm1, lm2;
        scan2(lm1, lm2);
        for (int k = 0; k < KK; ++k) {
            unsigned key = (unsigned)(lm1 >> 32);
            unsigned bk = key;
            #pragma unroll
            for (int s = 1; s < 64; s <<= 1) {
                unsigned ob = __shfl_xor(bk, s, 64);
                bk = ob < bk ? ob : bk;
            }
            u64 winners = __ballot(key == bk);
            int wl;
            u64 best;
            if (__popcll(winners) == 1) {
                wl = (int)(__ffsll((unsigned long long)winners) - 1);
                best = __shfl(lm1, wl, 64);
            } else {
                // exact tie-break: lowest global j among equal keys
                unsigned jc = (key == bk) ? (unsigned)lm1 : 0xFFFFFFFFu;
                unsigned bj = jc;
                #pragma unroll
                for (int s = 1; s < 64; s <<= 1) {
                    unsigned oj = __shfl_xor(bj, s, 64);
                    bj = oj < bj ? oj : bj;
                }
                winners = __ballot(key == bk && (unsigned)lm1 == bj);
                wl = (int)(__ffsll((unsigned long long)winners) - 1);
                best = ((u64)bk << 32) | bj;
            }
            if (lane == 0) outp[k] = best;
            if (lane == wl) {
                drow[(unsigned)best & 1023u] = 0xFFFFFFFFu;   // pop (local idx)
                if (lm2 != ~0ull) { lm1 = lm2; lm2 = ~0ull; }
                else scan2(lm1, lm2);
            }
        }
    }
}

// ---------------- merge per-half top-20 lists -> idx ----------------
__global__ void knn_merge_kernel(const u64* __restrict__ halfsel,
                                 int* __restrict__ idx) {
    long row = (long)blockIdx.x * 256 + threadIdx.x;   // 0 .. BB*Nn-1
    const u64* p = halfsel + row * 2 * KK;
    int* o = idx + row * KK;
    int ia = 0, ib = 0;
    #pragma unroll
    for (int k = 0; k < KK; ++k) {
        u64 a = p[ia], bq = p[KK + ib];
        if (a < bq) { o[k] = (int)(unsigned)a; ++ia; }
        else        { o[k] = (int)(unsigned)bq; ++ib; }
    }
}

// ---------------- projection GEMM: Z[m][0..2Co) = sum_c x[c][m] * Wstk[c][.] ----
template<int CIN, int CO2>
__global__ void __launch_bounds__(256)
proj_gemm(const float* __restrict__ x, long bst,
          const float* __restrict__ Wstk, float* __restrict__ Z) {
    const int tid = threadIdx.x;
    const int b  = blockIdx.x & 7;
    const int mt = (blockIdx.x >> 3) & 31;
    const int ot = blockIdx.x >> 8;
    const int mi = mt * 64 + (tid & 15) * 4;
    const int oj = ot * 64 + (tid >> 4) * 4;
    const float* xb = x + (long)b * bst + mi;

    float acc[4][4];
    #pragma unroll
    for (int r = 0; r < 4; ++r)
        #pragma unroll
        for (int j = 0; j < 4; ++j) acc[r][j] = 0.f;

    #pragma unroll 4
    for (int c = 0; c < CIN; ++c) {
        float4 xv = *(const float4*)(xb + (long)c * Nn);
        float4 wv = *(const float4*)(Wstk + (long)c * CO2 + oj);
        acc[0][0] += xv.x * wv.x; acc[0][1] += xv.x * wv.y; acc[0][2] += xv.x * wv.z; acc[0][3] += xv.x * wv.w;
        acc[1][0] += xv.y * wv.x; acc[1][1] += xv.y * wv.y; acc[1][2] += xv.y * wv.z; acc[1][3] += xv.y * wv.w;
        acc[2][0] += xv.z * wv.x; acc[2][1] += xv.z * wv.y; acc[2][2] += xv.z * wv.z; acc[2][3] += xv.z * wv.w;
        acc[3][0] += xv.w * wv.x; acc[3][1] += xv.w * wv.y; acc[3][2] += xv.w * wv.z; acc[3][3] += xv.w * wv.w;
    }
    float* Zb = Z + (long)b * 2048 * CO2;
    #pragma unroll
    for (int r = 0; r < 4; ++r) {
        float4 v = make_float4(acc[r][0], acc[r][1], acc[r][2], acc[r][3]);
        *(float4*)(Zb + (long)(mi + r) * CO2 + oj) = v;
    }
}

// ---------------- gather-max epilogue (also emits bf16 n-major copy) ----------------
template<int CO>
__global__ void __launch_bounds__(256)
gather_max(const float* __restrict__ Z, const int* __restrict__ idx,
           float* __restrict__ out, long obst,
           __hip_bfloat16* __restrict__ xbT, int coff) {
    constexpr int CO2 = 2 * CO;
    constexpr int VEC = CO / 64;
    __shared__ float tile[16][CO + 4];
    __shared__ int ji[16][KK];
    const int tid = threadIdx.x;
    const int b  = blockIdx.x & 7;
    const int n0 = (blockIdx.x >> 3) * 16;
    const float* Zb = Z + (long)b * 2048 * CO2;

    for (int t = tid; t < 16 * KK; t += 256) {
        int nn = t / KK, k = t - nn * KK;
        ji[nn][k] = idx[((long)b * Nn + n0 + nn) * KK + k];
    }
    __syncthreads();

    const int w = tid >> 6, lane = tid & 63;
    for (int i = 0; i < 4; ++i) {
        int nl = w * 4 + i, n = n0 + nl;
        float mx[VEC];
        #pragma unroll
        for (int v = 0; v < VEC; ++v) mx[v] = -FLT_MAX;
        for (int k = 0; k < KK; ++k) {
            int m = ji[nl][k];
            const float* zr = Zb + (long)m * CO2 + lane * VEC;
            #pragma unroll
            for (int v = 0; v < VEC; ++v) mx[v] = fmaxf(mx[v], zr[v]);
        }
        const float* zc = Zb + (long)n * CO2 + CO + lane * VEC;
        __hip_bfloat16* xr = xbT + ((long)b * 2048 + n) * 512 + coff + lane * VEC;
        #pragma unroll
        for (int v = 0; v < VEC; ++v) {
            float y = mx[v] + zc[v];
            y = y > 0.f ? y : SLOPE * y;
            tile[nl][lane * VEC + v] = y;
            xr[v] = __float2bfloat16(y);
        }
    }
    __syncthreads();

    for (int r = tid; r < CO * 4; r += 256) {
        int o = r >> 2, q = r & 3;
        float4 vv;
        vv.x = tile[q * 4 + 0][o];
        vv.y = tile[q * 4 + 1][o];
        vv.z = tile[q * 4 + 2][o];
        vv.w = tile[q * 4 + 3][o];
        *(float4*)(out + (long)b * obst + (long)o * Nn + n0 + q * 4) = vv;
    }
}

// ---------------- Global conv via bf16 MFMA, fused max-over-n ----------------
__global__ void __launch_bounds__(256)
global_mfma(const __hip_bfloat16* __restrict__ Wgb,   // [1024][512]
            const __hip_bfloat16* __restrict__ xbT,   // [B][2048][512]
            float* __restrict__ partial) {            // [B][1024][NCH]
    const int tid = threadIdx.x;
    const int w = tid >> 6, lane = tid & 63;
    const int lm = lane & 15, quad = lane >> 4;
    const int b  = blockIdx.x >> 7;
    const int ot = (blockIdx.x >> 3) & 15;
    const int nb = blockIdx.x & 7;
    const int o0 = ot * 64;
    const int nbw = nb * 256 + w * 64;

    const __hip_bfloat16* Arow = Wgb + (long)(o0 + lm) * 512 + quad * 8;
    const __hip_bfloat16* Brow = xbT + ((long)b * 2048 + nbw + lm) * 512 + quad * 8;

    f32x4 acc[4][4];
    #pragma unroll
    for (int mt = 0; mt < 4; ++mt)
        #pragma unroll
        for (int nt = 0; nt < 4; ++nt)
            acc[mt][nt] = (f32x4){0.f, 0.f, 0.f, 0.f};

    #pragma unroll 2
    for (int kk = 0; kk < 512; kk += 32) {
        bf16x8 a[4], bb[4];
        #pragma unroll
        for (int mt = 0; mt < 4; ++mt)
            a[mt] = *(const bf16x8*)(const void*)(Arow + (long)mt * 16 * 512 + kk);
        #pragma unroll
        for (int nt = 0; nt < 4; ++nt)
            bb[nt] = *(const bf16x8*)(const void*)(Brow + (long)nt * 16 * 512 + kk);
        #pragma unroll
        for (int mt = 0; mt < 4; ++mt)
            #pragma unroll
            for (int nt = 0; nt < 4; ++nt)
                acc[mt][nt] = __builtin_amdgcn_mfma_f32_16x16x32_bf16(
                    a[mt], bb[nt], acc[mt][nt], 0, 0, 0);
    }

    // D mapping: col(n) = lane&15, row(m) = quad*4 + reg
    #pragma unroll
    for (int mt = 0; mt < 4; ++mt) {
        #pragma unroll
        for (int r = 0; r < 4; ++r) {
            float v = fmaxf(fmaxf(acc[mt][0][r], acc[mt][1][r]),
                            fmaxf(acc[mt][2][r], acc[mt][3][r]));
            #pragma unroll
            for (int s = 1; s < 16; s <<= 1)
                v = fmaxf(v, __shfl_xor(v, s, 16));
            if (lm == 0) {
                int o = o0 + mt * 16 + quad * 4 + r;
                partial[((long)b * 1024 + o) * NCH + nb * 4 + w] = v;
            }
        }
    }
}

// ---------------- final max over chunks + leaky ----------------
__global__ void gmax_kernel(const float* __restrict__ partial, float* __restrict__ out) {
    int i = blockIdx.x * 256 + threadIdx.x;   // 0..8191
    float m = -FLT_MAX;
    #pragma unroll
    for (int j = 0; j < NCH; ++j) m = fmaxf(m, partial[(long)i * NCH + j]);
    out[i] = m > 0.f ? m : SLOPE * m;
}

extern "C" void kernel_launch(void* const* d_in, const int* in_sizes, int n_in,
                              void* d_out, int out_size, void* d_ws, size_t ws_size,
                              hipStream_t stream) {
    const float* x  = (const float*)d_in[0];
    const float* W1 = (const float*)d_in[1];   // [64][6]
    const float* W2 = (const float*)d_in[2];   // [64][128]
    const float* W3 = (const float*)d_in[3];   // [128][128]
    const float* W4 = (const float*)d_in[4];   // [256][256]
    const float* Wg = (const float*)d_in[5];   // [1024][512]
    float* out = (float*)d_out;

    float* ws = (float*)d_ws;
    float* xcat = ws;                                       // 8*512*2048 f32
    int*   idxb = (int*)(xcat + (long)BB * 512 * Nn);       // 8*2048*20 int
    float* part = (float*)(idxb + (long)BB * Nn * KK);      // 8*1024*NCH f32
    float* ws1  = part + (long)BB * 1024 * NCH;             // 3*128
    float* ws2  = ws1 + 3 * 128;                            // 64*128
    float* ws3  = ws2 + 64 * 128;                           // 64*256
    float* ws4  = ws3 + 64 * 256;                           // 128*512
    __hip_bfloat16* Wgb = (__hip_bfloat16*)(ws4 + 128 * 512);   // 1024*512 bf16
    __hip_bfloat16* xbT = Wgb + (long)1024 * 512;               // 8*2048*512 bf16
    float* Z    = (float*)(xbT + (long)BB * Nn * 512);          // 8*2048*1024 f32
    u64* halfsel = (u64*)(Z + (long)BB * Nn * 1024);            // 8*2048*2*20 u64

    const long XB = (long)512 * Nn;   // xcat batch stride

    wstack_kernel<<<(64 * 3 + 255) / 256, 256, 0, stream>>>(W1, ws1, 64, 3);
    wstack_kernel<<<(64 * 64 + 255) / 256, 256, 0, stream>>>(W2, ws2, 64, 64);
    wstack_kernel<<<(128 * 64 + 255) / 256, 256, 0, stream>>>(W3, ws3, 128, 64);
    wstack_kernel<<<(256 * 128 + 255) / 256, 256, 0, stream>>>(W4, ws4, 256, 128);
    tobf16_kernel<<<(1024 * 512 + 255) / 256, 256, 0, stream>>>(Wg, Wgb, 1024 * 512);

    const int knn_grid = BB * 256 * 2;     // 4096 blocks, 256 threads
    const int mrg_grid = BB * Nn / 256;    // 64
    const int ep_grid  = (Nn / 16) * BB;   // 1024

    // stage 1: x (C=3) -> xcat[0:64], xbT[:, 0:64)
    knn_dist_kernel<3><<<knn_grid, 256, 0, stream>>>(x, (long)3 * Nn, halfsel);
    knn_merge_kernel<<<mrg_grid, 256, 0, stream>>>(halfsel, idxb);
    proj_gemm<3, 128><<<8 * 32 * 2, 256, 0, stream>>>(x, (long)3 * Nn, ws1, Z);
    gather_max<64><<<ep_grid, 256, 0, stream>>>(Z, idxb, xcat, XB, xbT, 0);
    // stage 2
    knn_dist_kernel<64><<<knn_grid, 256, 0, stream>>>(xcat, XB, halfsel);
    knn_merge_kernel<<<mrg_grid, 256, 0, stream>>>(halfsel, idxb);
    proj_gemm<64, 128><<<8 * 32 * 2, 256, 0, stream>>>(xcat, XB, ws2, Z);
    gather_max<64><<<ep_grid, 256, 0, stream>>>(Z, idxb, xcat + (long)64 * Nn, XB, xbT, 64);
    // stage 3
    knn_dist_kernel<64><<<knn_grid, 256, 0, stream>>>(xcat + (long)64 * Nn, XB, halfsel);
    knn_merge_kernel<<<mrg_grid, 256, 0, stream>>>(halfsel, idxb);
    proj_gemm<64, 256><<<8 * 32 * 4, 256, 0, stream>>>(xcat + (long)64 * Nn, XB, ws3, Z);
    gather_max<128><<<ep_grid, 256, 0, stream>>>(Z, idxb, xcat + (long)128 * Nn, XB, xbT, 128);
    // stage 4
    knn_dist_kernel<128><<<knn_grid, 256, 0, stream>>>(xcat + (long)128 * Nn, XB, halfsel);
    knn_merge_kernel<<<mrg_grid, 256, 0, stream>>>(halfsel, idxb);
    proj_gemm<128, 512><<<8 * 32 * 8, 256, 0, stream>>>(xcat + (long)128 * Nn, XB, ws4, Z);
    gather_max<256><<<ep_grid, 256, 0, stream>>>(Z, idxb, xcat + (long)256 * Nn, XB, xbT, 256);

    // global conv via MFMA (fused max) + final reduce
    global_mfma<<<BB * 16 * 8, 256, 0, stream>>>(Wgb, xbT, part);
    gmax_kernel<<<BB * 1024 / 256, 256, 0, stream>>>(part, out);
}

// Round 8
// 827.017 us; speedup vs baseline: 1.0272x; 1.0272x over previous
//
#include <hip/hip_runtime.h>
#include <hip/hip_bf16.h>
#include <cfloat>

#define Nn 2048
#define KK 20
#define BB 8
#define SLOPE 0.2f
#define NCH 32   // partial chunks in global conv (8 nblk x 4 waves)

typedef __bf16 bf16x8 __attribute__((ext_vector_type(8)));
typedef float f32x4 __attribute__((ext_vector_type(4)));
typedef unsigned long long u64;

// ---------------- fused prep: wstack W1..W4 + bf16(Wg) ----------------
// Wstk[c][o] = W[o][c]; Wstk[c][Co+o] = W[o][C+c] - W[o][c]
__device__ __forceinline__ void wstack_elem(const float* W, float* Wstk,
                                            int Co, int C, int i) {
    int o = i / C, c = i - o * C;
    float a = W[(long)o * 2 * C + c];
    float bb = W[(long)o * 2 * C + C + c];
    Wstk[(long)c * 2 * Co + o] = a;
    Wstk[(long)c * 2 * Co + Co + o] = bb - a;
}

__global__ void prep_kernel(const float* __restrict__ W1, const float* __restrict__ W2,
                            const float* __restrict__ W3, const float* __restrict__ W4,
                            const float* __restrict__ Wg,
                            float* __restrict__ ws1, float* __restrict__ ws2,
                            float* __restrict__ ws3, float* __restrict__ ws4,
                            __hip_bfloat16* __restrict__ Wgb) {
    int i = blockIdx.x * 256 + threadIdx.x;
    if (i < 192) { wstack_elem(W1, ws1, 64, 3, i); return; }
    i -= 192;
    if (i < 4096) { wstack_elem(W2, ws2, 64, 64, i); return; }
    i -= 4096;
    if (i < 8192) { wstack_elem(W3, ws3, 128, 64, i); return; }
    i -= 8192;
    if (i < 32768) { wstack_elem(W4, ws4, 256, 128, i); return; }
    i -= 32768;
    if (i < 1024 * 512) Wgb[i] = __float2bfloat16(Wg[i]);
}

// ---------------- per-point squared norm: xx[b][j] = sum_c x[c][j]^2 ----------------
__global__ void sqnorm_kernel(const float* __restrict__ x, long bst, int C,
                              float* __restrict__ xx) {
    int gid = blockIdx.x * 256 + threadIdx.x;   // 0 .. BB*Nn-1
    int b = gid >> 11, j = gid & (Nn - 1);
    const float* xb = x + (long)b * bst + j;
    float a = 0.f;
    for (int c = 0; c < C; ++c) {
        float v = xb[(long)c * Nn];
        a = fmaf(v, v, a);
    }
    xx[gid] = a;
}

// order-preserving float-bits -> u32 map (works for negatives)
__device__ __forceinline__ unsigned fkey(float f) {
    unsigned u = __float_as_uint(f);
    return u ^ (((unsigned)((int)u >> 31)) | 0x80000000u);
}

// ---------------- KNN: 8 rows per block, 512 threads ----------------
// dist order == xx_j - 2*dot(x_n, x_j)  (per-row const xx_n dropped: order-invariant)
template<int C>
__global__ void __launch_bounds__(512)
knn_kernel(const float* __restrict__ x, long bstride,
           const float* __restrict__ xx, int* __restrict__ idx) {
    __shared__ unsigned dist[8][Nn];   // XOR-mapped float keys; 64 KB
    const int tid = threadIdx.x;
    const int b  = blockIdx.x >> 8;         // 256 blocks per b
    const int n0 = (blockIdx.x & 255) * 8;
    const float* xb = x + (long)b * bstride;
    const float* xxb = xx + (long)b * Nn;

    // distance phase: thread owns j = q*512 + tid, q = 0..3
    float acc[8][4];
    #pragma unroll
    for (int r = 0; r < 8; ++r)
        #pragma unroll
        for (int q = 0; q < 4; ++q) acc[r][q] = 0.f;

    #pragma unroll 4
    for (int c = 0; c < C; ++c) {
        const float* xp = xb + (long)c * Nn;
        float xv0 = xp[tid];
        float xv1 = xp[tid + 512];
        float xv2 = xp[tid + 1024];
        float xv3 = xp[tid + 1536];
        float4 c0 = *(const float4*)(xp + n0);      // block-uniform -> scalar pipe
        float4 c1 = *(const float4*)(xp + n0 + 4);
        acc[0][0] += c0.x * xv0; acc[0][1] += c0.x * xv1; acc[0][2] += c0.x * xv2; acc[0][3] += c0.x * xv3;
        acc[1][0] += c0.y * xv0; acc[1][1] += c0.y * xv1; acc[1][2] += c0.y * xv2; acc[1][3] += c0.y * xv3;
        acc[2][0] += c0.z * xv0; acc[2][1] += c0.z * xv1; acc[2][2] += c0.z * xv2; acc[2][3] += c0.z * xv3;
        acc[3][0] += c0.w * xv0; acc[3][1] += c0.w * xv1; acc[3][2] += c0.w * xv2; acc[3][3] += c0.w * xv3;
        acc[4][0] += c1.x * xv0; acc[4][1] += c1.x * xv1; acc[4][2] += c1.x * xv2; acc[4][3] += c1.x * xv3;
        acc[5][0] += c1.y * xv0; acc[5][1] += c1.y * xv1; acc[5][2] += c1.y * xv2; acc[5][3] += c1.y * xv3;
        acc[6][0] += c1.z * xv0; acc[6][1] += c1.z * xv1; acc[6][2] += c1.z * xv2; acc[6][3] += c1.z * xv3;
        acc[7][0] += c1.w * xv0; acc[7][1] += c1.w * xv1; acc[7][2] += c1.w * xv2; acc[7][3] += c1.w * xv3;
    }
    float xq0 = xxb[tid], xq1 = xxb[tid + 512], xq2 = xxb[tid + 1024], xq3 = xxb[tid + 1536];
    #pragma unroll
    for (int r = 0; r < 8; ++r) {
        dist[r][tid]        = fkey(fmaf(-2.f, acc[r][0], xq0));
        dist[r][tid + 512]  = fkey(fmaf(-2.f, acc[r][1], xq1));
        dist[r][tid + 1024] = fkey(fmaf(-2.f, acc[r][2], xq2));
        dist[r][tid + 1536] = fkey(fmaf(-2.f, acc[r][3], xq3));
    }
    __syncthreads();

    // selection: wave w owns row w; lazy per-lane top-2 in registers.
    // Per round: u32 min butterfly + ballot winner-lane (+ exact j tie-break).
    const int w = tid >> 6, lane = tid & 63;
    unsigned* drow = dist[w];
    int* outp = idx + ((long)b * Nn + n0 + w) * KK;

    auto scan2 = [&](u64& m1, u64& m2) {
        m1 = ~0ull; m2 = ~0ull;
        #pragma unroll
        for (int jj = 0; jj < 8; ++jj) {
            int j4 = (jj * 64 + lane) * 4;
            uint4 v = *(const uint4*)(drow + j4);
            u64 kk0 = ((u64)v.x << 32) | (unsigned)(j4 + 0);
            u64 kk1 = ((u64)v.y << 32) | (unsigned)(j4 + 1);
            u64 kk2 = ((u64)v.z << 32) | (unsigned)(j4 + 2);
            u64 kk3 = ((u64)v.w << 32) | (unsigned)(j4 + 3);
            u64 hi;
            hi = kk0 > m1 ? kk0 : m1; m1 = kk0 < m1 ? kk0 : m1; m2 = hi < m2 ? hi : m2;
            hi = kk1 > m1 ? kk1 : m1; m1 = kk1 < m1 ? kk1 : m1; m2 = hi < m2 ? hi : m2;
            hi = kk2 > m1 ? kk2 : m1; m1 = kk2 < m1 ? kk2 : m1; m2 = hi < m2 ? hi : m2;
            hi = kk3 > m1 ? kk3 : m1; m1 = kk3 < m1 ? kk3 : m1; m2 = hi < m2 ? hi : m2;
        }
    };

    u64 lm1, lm2;
    scan2(lm1, lm2);
    for (int k = 0; k < KK; ++k) {
        unsigned key = (unsigned)(lm1 >> 32);
        unsigned bk = key;
        #pragma unroll
        for (int s = 1; s < 64; s <<= 1) {
            unsigned ob = __shfl_xor(bk, s, 64);
            bk = ob < bk ? ob : bk;
        }
        u64 winners = __ballot(key == bk);
        int wl;
        int bi;
        if (__popcll(winners) == 1) {
            wl = (int)(__ffsll((unsigned long long)winners) - 1);
            bi = (int)__shfl((unsigned)lm1, wl, 64);
        } else {
            // exact tie-break: lowest j among equal keys
            unsigned jc = (key == bk) ? (unsigned)lm1 : 0xFFFFFFFFu;
            unsigned bj = jc;
            #pragma unroll
            for (int s = 1; s < 64; s <<= 1) {
                unsigned oj = __shfl_xor(bj, s, 64);
                bj = oj < bj ? oj : bj;
            }
            winners = __ballot(key == bk && (unsigned)lm1 == bj);
            wl = (int)(__ffsll((unsigned long long)winners) - 1);
            bi = (int)bj;
        }
        if (lane == 0) outp[k] = bi;
        if (lane == wl) {
            drow[bi] = 0xFFFFFFFFu;  // consumed sentinel
            if (lm2 != ~0ull) { lm1 = lm2; lm2 = ~0ull; }
            else scan2(lm1, lm2);    // rare: lane's 3rd+ win since last refill
        }
    }
}

// ---------------- projection GEMM: Z[m][0..2Co) = sum_c x[c][m] * Wstk[c][.] ----
template<int CIN, int CO2>
__global__ void __launch_bounds__(256)
proj_gemm(const float* __restrict__ x, long bst,
          const float* __restrict__ Wstk, float* __restrict__ Z) {
    const int tid = threadIdx.x;
    const int b  = blockIdx.x & 7;
    const int mt = (blockIdx.x >> 3) & 31;
    const int ot = blockIdx.x >> 8;
    const int mi = mt * 64 + (tid & 15) * 4;
    const int oj = ot * 64 + (tid >> 4) * 4;
    const float* xb = x + (long)b * bst + mi;

    float acc[4][4];
    #pragma unroll
    for (int r = 0; r < 4; ++r)
        #pragma unroll
        for (int j = 0; j < 4; ++j) acc[r][j] = 0.f;

    #pragma unroll 4
    for (int c = 0; c < CIN; ++c) {
        float4 xv = *(const float4*)(xb + (long)c * Nn);
        float4 wv = *(const float4*)(Wstk + (long)c * CO2 + oj);
        acc[0][0] += xv.x * wv.x; acc[0][1] += xv.x * wv.y; acc[0][2] += xv.x * wv.z; acc[0][3] += xv.x * wv.w;
        acc[1][0] += xv.y * wv.x; acc[1][1] += xv.y * wv.y; acc[1][2] += xv.y * wv.z; acc[1][3] += xv.y * wv.w;
        acc[2][0] += xv.z * wv.x; acc[2][1] += xv.z * wv.y; acc[2][2] += xv.z * wv.z; acc[2][3] += xv.z * wv.w;
        acc[3][0] += xv.w * wv.x; acc[3][1] += xv.w * wv.y; acc[3][2] += xv.w * wv.z; acc[3][3] += xv.w * wv.w;
    }
    float* Zb = Z + (long)b * 2048 * CO2;
    #pragma unroll
    for (int r = 0; r < 4; ++r) {
        float4 v = make_float4(acc[r][0], acc[r][1], acc[r][2], acc[r][3]);
        *(float4*)(Zb + (long)(mi + r) * CO2 + oj) = v;
    }
}

// ---------------- gather-max epilogue (also emits bf16 n-major copy) ----------------
template<int CO>
__global__ void __launch_bounds__(256)
gather_max(const float* __restrict__ Z, const int* __restrict__ idx,
           float* __restrict__ out, long obst,
           __hip_bfloat16* __restrict__ xbT, int coff) {
    constexpr int CO2 = 2 * CO;
    constexpr int VEC = CO / 64;
    __shared__ float tile[16][CO + 4];
    __shared__ int ji[16][KK];
    const int tid = threadIdx.x;
    const int b  = blockIdx.x & 7;
    const int n0 = (blockIdx.x >> 3) * 16;
    const float* Zb = Z + (long)b * 2048 * CO2;

    for (int t = tid; t < 16 * KK; t += 256) {
        int nn = t / KK, k = t - nn * KK;
        ji[nn][k] = idx[((long)b * Nn + n0 + nn) * KK + k];
    }
    __syncthreads();

    const int w = tid >> 6, lane = tid & 63;
    for (int i = 0; i < 4; ++i) {
        int nl = w * 4 + i, n = n0 + nl;
        float mx[VEC];
        #pragma unroll
        for (int v = 0; v < VEC; ++v) mx[v] = -FLT_MAX;
        #pragma unroll 4
        for (int k = 0; k < KK; ++k) {
            int m = ji[nl][k];
            const float* zr = Zb + (long)m * CO2 + lane * VEC;
            #pragma unroll
            for (int v = 0; v < VEC; ++v) mx[v] = fmaxf(mx[v], zr[v]);
        }
        const float* zc = Zb + (long)n * CO2 + CO + lane * VEC;
        __hip_bfloat16* xr = xbT + ((long)b * 2048 + n) * 512 + coff + lane * VEC;
        #pragma unroll
        for (int v = 0; v < VEC; ++v) {
            float y = mx[v] + zc[v];
            y = y > 0.f ? y : SLOPE * y;
            tile[nl][lane * VEC + v] = y;
            xr[v] = __float2bfloat16(y);
        }
    }
    __syncthreads();

    for (int r = tid; r < CO * 4; r += 256) {
        int o = r >> 2, q = r & 3;
        float4 vv;
        vv.x = tile[q * 4 + 0][o];
        vv.y = tile[q * 4 + 1][o];
        vv.z = tile[q * 4 + 2][o];
        vv.w = tile[q * 4 + 3][o];
        *(float4*)(out + (long)b * obst + (long)o * Nn + n0 + q * 4) = vv;
    }
}

// ---------------- Global conv via bf16 MFMA, fused max-over-n ----------------
__global__ void __launch_bounds__(256)
global_mfma(const __hip_bfloat16* __restrict__ Wgb,   // [1024][512]
            const __hip_bfloat16* __restrict__ xbT,   // [B][2048][512]
            float* __restrict__ partial) {            // [B][1024][NCH]
    const int tid = threadIdx.x;
    const int w = tid >> 6, lane = tid & 63;
    const int lm = lane & 15, quad = lane >> 4;
    const int b  = blockIdx.x >> 7;
    const int ot = (blockIdx.x >> 3) & 15;
    const int nb = blockIdx.x & 7;
    const int o0 = ot * 64;
    const int nbw = nb * 256 + w * 64;

    const __hip_bfloat16* Arow = Wgb + (long)(o0 + lm) * 512 + quad * 8;
    const __hip_bfloat16* Brow = xbT + ((long)b * 2048 + nbw + lm) * 512 + quad * 8;

    f32x4 acc[4][4];
    #pragma unroll
    for (int mt = 0; mt < 4; ++mt)
        #pragma unroll
        for (int nt = 0; nt < 4; ++nt)
            acc[mt][nt] = (f32x4){0.f, 0.f, 0.f, 0.f};

    #pragma unroll 2
    for (int kk = 0; kk < 512; kk += 32) {
        bf16x8 a[4], bb[4];
        #pragma unroll
        for (int mt = 0; mt < 4; ++mt)
            a[mt] = *(const bf16x8*)(const void*)(Arow + (long)mt * 16 * 512 + kk);
        #pragma unroll
        for (int nt = 0; nt < 4; ++nt)
            bb[nt] = *(const bf16x8*)(const void*)(Brow + (long)nt * 16 * 512 + kk);
        #pragma unroll
        for (int mt = 0; mt < 4; ++mt)
            #pragma unroll
            for (int nt = 0; nt < 4; ++nt)
                acc[mt][nt] = __builtin_amdgcn_mfma_f32_16x16x32_bf16(
                    a[mt], bb[nt], acc[mt][nt], 0, 0, 0);
    }

    // D mapping: col(n) = lane&15, row(m) = quad*4 + reg
    #pragma unroll
    for (int mt = 0; mt < 4; ++mt) {
        #pragma unroll
        for (int r = 0; r < 4; ++r) {
            float v = fmaxf(fmaxf(acc[mt][0][r], acc[mt][1][r]),
                            fmaxf(acc[mt][2][r], acc[mt][3][r]));
            #pragma unroll
            for (int s = 1; s < 16; s <<= 1)
                v = fmaxf(v, __shfl_xor(v, s, 16));
            if (lm == 0) {
                int o = o0 + mt * 16 + quad * 4 + r;
                partial[((long)b * 1024 + o) * NCH + nb * 4 + w] = v;
            }
        }
    }
}

// ---------------- final max over chunks + leaky ----------------
__global__ void gmax_kernel(const float* __restrict__ partial, float* __restrict__ out) {
    int i = blockIdx.x * 256 + threadIdx.x;   // 0..8191
    float m = -FLT_MAX;
    #pragma unroll
    for (int j = 0; j < NCH; ++j) m = fmaxf(m, partial[(long)i * NCH + j]);
    out[i] = m > 0.f ? m : SLOPE * m;
}

extern "C" void kernel_launch(void* const* d_in, const int* in_sizes, int n_in,
                              void* d_out, int out_size, void* d_ws, size_t ws_size,
                              hipStream_t stream) {
    const float* x  = (const float*)d_in[0];
    const float* W1 = (const float*)d_in[1];   // [64][6]
    const float* W2 = (const float*)d_in[2];   // [64][128]
    const float* W3 = (const float*)d_in[3];   // [128][128]
    const float* W4 = (const float*)d_in[4];   // [256][256]
    const float* Wg = (const float*)d_in[5];   // [1024][512]
    float* out = (float*)d_out;

    float* ws = (float*)d_ws;
    float* xcat = ws;                                       // 8*512*2048 f32
    int*   idxb = (int*)(xcat + (long)BB * 512 * Nn);       // 8*2048*20 int
    float* part = (float*)(idxb + (long)BB * Nn * KK);      // 8*1024*NCH f32
    float* ws1  = part + (long)BB * 1024 * NCH;             // 3*128
    float* ws2  = ws1 + 3 * 128;                            // 64*128
    float* ws3  = ws2 + 64 * 128;                           // 64*256
    float* ws4  = ws3 + 64 * 256;                           // 128*512
    __hip_bfloat16* Wgb = (__hip_bfloat16*)(ws4 + 128 * 512);   // 1024*512 bf16
    __hip_bfloat16* xbT = Wgb + (long)1024 * 512;               // 8*2048*512 bf16
    float* Z    = (float*)(xbT + (long)BB * Nn * 512);          // 8*2048*512 f32
    float* xx   = Z + (long)BB * Nn * 512;                      // 8*2048 f32

    const long XB = (long)512 * Nn;   // xcat batch stride

    prep_kernel<<<(192 + 4096 + 8192 + 32768 + 1024 * 512 + 255) / 256, 256, 0, stream>>>(
        W1, W2, W3, W4, Wg, ws1, ws2, ws3, ws4, Wgb);

    const int knn_grid = BB * 256;         // 2048 blocks, 512 threads
    const int sq_grid  = BB * Nn / 256;    // 64
    const int ep_grid  = (Nn / 16) * BB;   // 1024

    // stage 1: x (C=3) -> xcat[0:64], xbT[:, 0:64)
    sqnorm_kernel<<<sq_grid, 256, 0, stream>>>(x, (long)3 * Nn, 3, xx);
    knn_kernel<3><<<knn_grid, 512, 0, stream>>>(x, (long)3 * Nn, xx, idxb);
    proj_gemm<3, 128><<<8 * 32 * 2, 256, 0, stream>>>(x, (long)3 * Nn, ws1, Z);
    gather_max<64><<<ep_grid, 256, 0, stream>>>(Z, idxb, xcat, XB, xbT, 0);
    // stage 2
    sqnorm_kernel<<<sq_grid, 256, 0, stream>>>(xcat, XB, 64, xx);
    knn_kernel<64><<<knn_grid, 512, 0, stream>>>(xcat, XB, xx, idxb);
    proj_gemm<64, 128><<<8 * 32 * 2, 256, 0, stream>>>(xcat, XB, ws2, Z);
    gather_max<64><<<ep_grid, 256, 0, stream>>>(Z, idxb, xcat + (long)64 * Nn, XB, xbT, 64);
    // stage 3
    sqnorm_kernel<<<sq_grid, 256, 0, stream>>>(xcat + (long)64 * Nn, XB, 64, xx);
    knn_kernel<64><<<knn_grid, 512, 0, stream>>>(xcat + (long)64 * Nn, XB, xx, idxb);
    proj_gemm<64, 256><<<8 * 32 * 4, 256, 0, stream>>>(xcat + (long)64 * Nn, XB, ws3, Z);
    gather_max<128><<<ep_grid, 256, 0, stream>>>(Z, idxb, xcat + (long)128 * Nn, XB, xbT, 128);
    // stage 4
    sqnorm_kernel<<<sq_grid, 256, 0, stream>>>(xcat + (long)128 * Nn, XB, 128, xx);
    knn_kernel<128><<<knn_grid, 512, 0, stream>>>(xcat + (long)128 * Nn, XB, xx, idxb);
    proj_gemm<128, 512><<<8 * 32 * 8, 256, 0, stream>>>(xcat + (long)128 * Nn, XB, ws4, Z);
    gather_max<256><<<ep_grid, 256, 0, stream>>>(Z, idxb, xcat + (long)256 * Nn, XB, xbT, 256);

    // global conv via MFMA (fused max) + final reduce
    global_mfma<<<BB * 16 * 8, 256, 0, stream>>>(Wgb, xbT, part);
    gmax_kernel<<<BB * 1024 / 256, 256, 0, stream>>>(part, out);
}